// Round 1
// baseline (100.981 us; speedup 1.0000x reference)
//
#include <hip/hip_runtime.h>

// MFHawkes: B=4, L=2048, K=100000, D=64
// Algebraic collapse:
//   lam_i   = |ab * exp(-ab*t_i) * (e_i . P_i) + u_i| + 1e-6,
//             P_i = sum_{j<i} e_j * exp(ab*t_j) * m_j            (D-vector prefix sum)
//   out[b]  = sum_i [-log(lam_i) + u_i*horizon] + (sum_i e_i) . V,
//             V   = sum_j e_j * (1 - exp(-ab*(t_last - t_j)))
// => O(B*L*D) work + 2MB random embedding gather.

#define BB 4
#define LL 2048
#define DD 64
#define CL 64            // chunk length
#define NC (LL / CL)     // 32 chunks per batch

// ---------------------------------------------------------------------------
// k1: per-chunk staging + partial sums.
// grid = BB*NC blocks, 64 threads (lane = dim d).
// ---------------------------------------------------------------------------
__global__ __launch_bounds__(64) void k1_stage(
    const int* __restrict__ ids, const float* __restrict__ times,
    const float* __restrict__ mask, const float* __restrict__ emb,
    const float* __restrict__ u_table, const float* __restrict__ beta,
    float* __restrict__ Ebuf, float* __restrict__ S, float* __restrict__ Ep,
    float* __restrict__ Vp, float* __restrict__ UK)
{
    const int blk = blockIdx.x;
    const int b = blk / NC, c = blk % NC;
    const int d = threadIdx.x;            // 0..63
    const int j0 = c * CL;

    const float ab = fabsf(beta[0]);
    const float tl = times[b * LL + LL - 1] * 1e-4f;
    const float cexp = expf(-ab * tl);    // exp(-ab * t_last)

    // per-lane scalars for j = j0 + lane (coalesced), broadcast below via shfl
    const int   myid = ids  [b * LL + j0 + d];
    const float myt  = times[b * LL + j0 + d] * 1e-4f;
    const float mym  = mask [b * LL + j0 + d];

    // u_k staging: lane j stores its own
    UK[b * LL + j0 + d] = fabsf(u_table[myid]);

    float s = 0.f, ep = 0.f, vp = 0.f;
#pragma unroll 16
    for (int jj = 0; jj < CL; ++jj) {
        const int   id = __shfl(myid, jj);
        const float t  = __shfl(myt,  jj);
        const float m  = __shfl(mym,  jj);
        const float e  = emb[(long)id * DD + d];   // random row gather, coalesced over d
        const float w  = expf(ab * t);             // exp(ab * t_j) in [1, 1.105]
        Ebuf[(b * LL + j0 + jj) * DD + d] = e;     // coalesced stage for k2
        s  += e * w * m;                           // f_j = e_j * w_j * m_j
        ep += e;
        vp += e * (1.f - cexp * w);                // e_j * (1 - exp(-ab*(t_last-t_j)))
    }
    S [(b * NC + c) * DD + d] = s;
    Ep[(b * NC + c) * DD + d] = ep;
    Vp[(b * NC + c) * DD + d] = vp;
}

// ---------------------------------------------------------------------------
// k2: chunk-offset resum + intra-chunk scan + dot + epilogue.
// grid = BB*NC blocks, 64 threads.
// ---------------------------------------------------------------------------
__global__ __launch_bounds__(64) void k2_scan(
    const float* __restrict__ times, const float* __restrict__ mask,
    const float* __restrict__ beta,
    const float* __restrict__ Ebuf, const float* __restrict__ S,
    const float* __restrict__ Ep, const float* __restrict__ Vp,
    const float* __restrict__ UK, float* __restrict__ out)
{
    __shared__ float E [CL][DD + 1];   // +1 pad: 2-way bank alias only (free)
    __shared__ float LP[CL][DD + 1];   // inclusive-of-offset exclusive prefix
    __shared__ float wm[CL];

    const int blk = blockIdx.x;
    const int b = blk / NC, c = blk % NC;
    const int lane = threadIdx.x;      // 0..63
    const int j0 = c * CL;

    const float ab = fabsf(beta[0]);
    const float tl = times[b * LL + LL - 1] * 1e-4f;
    const float t1 = times[b * LL + 1] * 1e-4f;
    const float horizon = tl - t1;

    // stage E from ws (coalesced)
#pragma unroll 8
    for (int j = 0; j < CL; ++j)
        E[j][lane] = Ebuf[(b * LL + j0 + j) * DD + lane];

    // per-row weight w_j * m_j
    const float ti = times[b * LL + j0 + lane] * 1e-4f;
    wm[lane] = expf(ab * ti) * mask[b * LL + j0 + lane];

    // exclusive cross-chunk offset: O_d = sum_{c'<c} S[b,c',d]
    float run = 0.f;
    for (int cc = 0; cc < c; ++cc)
        run += S[(b * NC + cc) * DD + lane];

    __syncthreads();

    // intra-chunk exclusive scan along rows (lane = dim d)
#pragma unroll 8
    for (int i = 0; i < CL; ++i) {
        LP[i][lane] = run;
        run += E[i][lane] * wm[i];     // wm[i] is an LDS broadcast (free)
    }
    __syncthreads();

    // dot phase (lane = row i): dotP = e_i . P_i
    float acc = 0.f;
#pragma unroll
    for (int k = 0; k < DD; ++k)
        acc += E[lane][k] * LP[lane][k];

    const float s1  = ab * expf(-ab * ti) * acc;
    const float uk  = UK[b * LL + j0 + lane];
    const float lam = fabsf(s1 + uk) + 1e-6f;
    float contrib = -logf(lam) + uk * horizon;

    // one block per batch also folds in (sum_i e_i) . V
    if (c == 0) {
        float et = 0.f, vt = 0.f;
        for (int cc = 0; cc < NC; ++cc) {
            et += Ep[(b * NC + cc) * DD + lane];
            vt += Vp[(b * NC + cc) * DD + lane];
        }
        contrib += et * vt;            // reduced across lanes below
    }

    // butterfly wave reduction over 64 lanes
#pragma unroll
    for (int off = 32; off > 0; off >>= 1)
        contrib += __shfl_xor(contrib, off);

    if (lane == 0) atomicAdd(&out[b], contrib);
}

// ---------------------------------------------------------------------------
extern "C" void kernel_launch(void* const* d_in, const int* in_sizes, int n_in,
                              void* d_out, int out_size, void* d_ws, size_t ws_size,
                              hipStream_t stream)
{
    const int*   ids     = (const int*)  d_in[0];
    const float* times   = (const float*)d_in[1];
    const float* mask    = (const float*)d_in[2];
    const float* emb     = (const float*)d_in[3];
    const float* u_table = (const float*)d_in[4];
    const float* beta    = (const float*)d_in[5];
    float* outp = (float*)d_out;

    float* ws   = (float*)d_ws;
    float* Ebuf = ws;                          // B*L*D   = 524288 floats
    float* S    = Ebuf + BB * LL * DD;         // B*NC*D  = 8192
    float* Ep   = S    + BB * NC * DD;         // 8192
    float* Vp   = Ep   + BB * NC * DD;         // 8192
    float* UK   = Vp   + BB * NC * DD;         // B*L     = 8192

    hipMemsetAsync(d_out, 0, out_size * sizeof(float), stream);

    k1_stage<<<BB * NC, 64, 0, stream>>>(ids, times, mask, emb, u_table, beta,
                                         Ebuf, S, Ep, Vp, UK);
    k2_scan<<<BB * NC, 64, 0, stream>>>(times, mask, beta,
                                        Ebuf, S, Ep, Vp, UK, outp);
}